// Round 13
// baseline (415.029 us; speedup 1.0000x reference)
//
#include <hip/hip_runtime.h>
#include <hip/hip_bf16.h>

#define B_ 128
#define T_ 512
#define BIN_ 24
#define D_ 256
#define S_ 128
#define L_ 2
#define BT_ (B_*T_)

typedef __hip_bfloat16 bf16;
typedef __hip_bfloat162 bf162;
typedef __attribute__((ext_vector_type(8))) short bf16x8;
typedef __attribute__((ext_vector_type(4))) short s16x4;
typedef __attribute__((ext_vector_type(4))) float f32x4;

__device__ __forceinline__ float b2f(bf16 x){ return __bfloat162float(x); }
__device__ __forceinline__ bf16 f2b(float x){ return __float2bfloat16(x); }
__device__ __forceinline__ float swish(float v){
  float e = __builtin_amdgcn_exp2f(-1.442695040888963f * v);
  return v * __builtin_amdgcn_rcpf(1.f + e);
}

// ---------------- tables: sinusoid PE (scaled) + rope sin/cos ----------------
__global__ void tables_kernel(const float* pe_scale_ptr, float* pe_tab, float* rs, float* rc) {
  int t = blockIdx.x;      // 0..511
  int j = threadIdx.x;     // 64 threads
  float ps = pe_scale_ptr[0];
  const float LOG1E4 = 9.210340371976184f;
  if (j < 64) {
    float inv = expf(-LOG1E4 * (float)j / 64.f);   // rope: 10000^(-2j/128)
    float ang = (float)t * inv;
    rs[t*64 + j] = sinf(ang);
    rc[t*64 + j] = cosf(ang);
  }
  if (j < BIN_) {
    int jj = (j < 12) ? j : (j - 12);
    float inv = expf(-LOG1E4 * (float)jj / 11.f);
    float ang = (float)t * inv;
    pe_tab[t*BIN_ + j] = ps * ((j < 12) ? sinf(ang) : cosf(ang));
  }
}

// ---------------- prep: W1 [2][256][640] -> W1t bf16 [2][640][256]; W2 likewise ----
__global__ __launch_bounds__(256) void prep_kernel(const float* W1, const float* W2,
                                                   bf16* W1t, bf16* W2t) {
  int idx = blockIdx.x*256 + threadIdx.x;
  if (idx < 2*256*640) {
    int l = idx / (256*640); int rem = idx % (256*640);
    int k = rem / 640; int n = rem % 640;
    W1t[(size_t)l*640*256 + n*256 + k] = f2b(W1[idx]);
  }
  if (idx < 2*256*256) {
    int l = idx >> 16; int rem = idx & 65535;
    int k = rem >> 8; int n = rem & 255;
    W2t[(size_t)l*65536 + n*256 + k] = f2b(W2[idx]);
  }
}

// ---------------- init: zero rms1 + pooled_raw ----------------
__global__ __launch_bounds__(256) void init_kernel(float* rms1, float* pooled_raw) {
  int i = blockIdx.x*256 + threadIdx.x;
  if (i < BT_) rms1[i] = 0.f;
  if (i < B_*D_) pooled_raw[i] = 0.f;
}

// ---------------- embed: h,hb = swish((x+pe)@W_in+b_in); rms0[row]=sum(h^2) --------
__global__ __launch_bounds__(256) void embed_kernel(const float* x, const float* pe_tab,
                const float* W_in, const float* b_in, float* h, float* rms0, bf16* hb) {
  __shared__ float xr[8][BIN_];
  __shared__ float wsum[4][8];
  int tid = threadIdx.x;
  int row0 = blockIdx.x * 8;
  if (tid < 8*BIN_) {
    int r = tid / BIN_, k = tid % BIN_;
    int row = row0 + r;
    int t = row & (T_-1);
    xr[r][k] = x[(size_t)row*BIN_ + k] + pe_tab[t*BIN_ + k];
  }
  __syncthreads();
  int d = tid;
  float bi = b_in[d];
  float acc[8];
  #pragma unroll
  for (int r=0;r<8;r++) acc[r]=bi;
  #pragma unroll
  for (int k=0;k<BIN_;k++){
    float w = W_in[k*D_ + d];
    #pragma unroll
    for (int r=0;r<8;r++) acc[r] += xr[r][k]*w;
  }
  float sq[8];
  #pragma unroll
  for (int r=0;r<8;r++){
    float v = swish(acc[r]);
    h[(size_t)(row0+r)*D_ + d] = v;
    hb[(size_t)(row0+r)*D_ + d] = f2b(v);
    sq[r] = v*v;
  }
  #pragma unroll
  for (int off=1; off<64; off<<=1)
    #pragma unroll
    for (int r=0;r<8;r++) sq[r] += __shfl_xor(sq[r], off);
  if ((tid&63)==0)
    #pragma unroll
    for (int r=0;r<8;r++) wsum[tid>>6][r] = sq[r];
  __syncthreads();
  if (tid < 8) rms0[row0+tid] = wsum[0][tid]+wsum[1][tid]+wsum[2][tid]+wsum[3][tid];
}

// ---------------- gemm1 (MFMA, LDS-staged bf16): [u|Vt_g|rope->q,k] = swish(rms(h)@W1+b1)
// bx<2: u out; bx 2,3: V transposed via Ovl -> Vtg; bx 4: base via Ovl -> fused rope -> q,k.
__global__ __launch_bounds__(256) void gemm1_mfma(const bf16* A, const bf16* Bt,
      const float* bias, const float* rmsraw, const float* norm_scale, int l,
      const float* gamma, const float* beta, const float* rs, const float* rc,
      bf16* u, bf16* Vtg, bf16* q, bf16* k) {
  __shared__ bf16 As[128*72];
  __shared__ bf16 Bs[128*72];
  bf16* Ovl = As; // [128][136] overlay, valid after k-loop

  int tid = threadIdx.x;
  int w = tid>>6, lane = tid&63, r = lane&15, g = lane>>4;
  int wr = w>>1, wc = w&1;
  int dd = blockIdx.x; int xcd = dd&7, slot = dd>>3;
  int panel = xcd*64 + slot/5; int bx = slot%5;
  int row0 = panel*128, col0 = bx*128;

  f32x4 acc[4][4];
  #pragma unroll
  for (int i=0;i<4;i++)
    #pragma unroll
    for (int j=0;j<4;j++) acc[i][j] = (f32x4){0.f,0.f,0.f,0.f};

  for (int k0=0; k0<D_; k0+=64) {
    #pragma unroll
    for (int i=0;i<4;i++){
      int id = i*256 + tid; int tr = id>>3, tc = id&7;
      *(bf16x8*)(As + tr*72 + tc*8) = *(const bf16x8*)(A  + (size_t)(row0+tr)*D_ + k0 + tc*8);
      *(bf16x8*)(Bs + tr*72 + tc*8) = *(const bf16x8*)(Bt + (size_t)(col0+tr)*D_ + k0 + tc*8);
    }
    __syncthreads();
    #pragma unroll
    for (int kk=0; kk<2; kk++){
      bf16x8 a[4], b[4];
      #pragma unroll
      for (int i=0;i<4;i++){
        a[i] = *(const bf16x8*)(As + (64*wr+16*i+r)*72 + kk*32 + g*8);
        b[i] = *(const bf16x8*)(Bs + (64*wc+16*i+r)*72 + kk*32 + g*8);
      }
      #pragma unroll
      for (int i=0;i<4;i++)
        #pragma unroll
        for (int j=0;j<4;j++)
          acc[i][j] = __builtin_amdgcn_mfma_f32_16x16x32_bf16(a[i], b[j], acc[i][j], 0,0,0);
    }
    __syncthreads();
  }

  float ns = norm_scale[l];
  #pragma unroll
  for (int i=0;i<4;i++){
    size_t grow0 = row0 + 64*wr + 16*i + 4*g;
    float4 rv = *(const float4*)(rmsraw + grow0);
    float sc[4];
    sc[0] = rsqrtf(rv.x*(1.f/D_) + 1e-6f) * ns;
    sc[1] = rsqrtf(rv.y*(1.f/D_) + 1e-6f) * ns;
    sc[2] = rsqrtf(rv.z*(1.f/D_) + 1e-6f) * ns;
    sc[3] = rsqrtf(rv.w*(1.f/D_) + 1e-6f) * ns;
    #pragma unroll
    for (int j=0;j<4;j++){
      int gcol = col0 + 64*wc + 16*j + r;
      float bv = bias[gcol];
      if (bx < 2) {
        #pragma unroll
        for (int reg=0; reg<4; reg++){
          float v = swish(acc[i][j][reg]*sc[reg] + bv);
          u[(grow0+reg)*D_ + gcol] = f2b(v);
        }
      } else if (bx < 4) {
        #pragma unroll
        for (int reg=0; reg<4; reg++){
          float v = swish(acc[i][j][reg]*sc[reg] + bv);
          Ovl[(64*wc+16*j+r)*136 + (64*wr+16*i+4*g+reg)] = f2b(v);
        }
      } else {
        // base block: Ovl[row][col] row-major
        #pragma unroll
        for (int reg=0; reg<4; reg++){
          float v = swish(acc[i][j][reg]*sc[reg] + bv);
          Ovl[(64*wr+16*i+4*g+reg)*136 + (64*wc+16*j+r)] = f2b(v);
        }
      }
    }
  }

  if (bx == 2 || bx == 3) {
    __syncthreads();
    size_t bb = row0 >> 9;
    int mg = row0 & 511;
    #pragma unroll
    for (int c=0;c<8;c++){
      int chunk = c*256 + tid;
      int e = chunk >> 4, mloc = (chunk & 15)*8;
      *(bf16x8*)(Vtg + bb*131072 + (size_t)(col0-256+e)*T_ + mg + mloc) =
        *(const bf16x8*)(Ovl + e*136 + mloc);
    }
  } else if (bx == 4) {
    __syncthreads();
    int lrow = tid>>1, h64 = (tid&1)*64;
    size_t grow = row0 + lrow;
    int t = (int)(grow & (T_-1));
    const float* rsb = rs + t*64;
    const float* rcb = rc + t*64;
    const float* gg = gamma + l*2*S_;
    const float* bt = beta  + l*2*S_;
    #pragma unroll
    for (int c=0;c<8;c++){
      int j0 = h64 + c*8;
      bf16x8 xj = *(const bf16x8*)(Ovl + lrow*136 + j0);
      bf16x8 xo = *(const bf16x8*)(Ovl + lrow*136 + (j0^64));
      bf16x8 qo, ko;
      #pragma unroll
      for (int e=0;e<8;e++){
        int j = j0 + e;
        int jm = j & 63;
        float sn = rsb[jm], cs = rcb[jm];
        float sgn = (j < 64) ? -1.f : 1.f;
        float v0 = b2f(((bf16*)&xj)[e]);
        float v1 = b2f(((bf16*)&xo)[e]);
        float xq = v0*gg[j]      + bt[j];
        float pq = v1*gg[j^64]   + bt[j^64];
        ((bf16*)&qo)[e] = f2b(xq*cs + sgn*pq*sn);
        float xk = v0*gg[S_+j]       + bt[S_+j];
        float pk = v1*gg[S_+(j^64)]  + bt[S_+(j^64)];
        ((bf16*)&ko)[e] = f2b(xk*cs + sgn*pk*sn);
      }
      *(bf16x8*)(q + grow*S_ + j0) = qo;
      *(bf16x8*)(k + grow*S_ + j0) = ko;
    }
  }
}

// ---------------- attn+gemm2 fused: h += (u ⊙ (relu(qk^T/512)^2 @ v)) @ W2 + b2
// LDS 77824 -> 2 blocks/CU. Phase 2: Os=PV via LDS, coalesced u-multiply pass,
// then Os @ W2 with Wt[128][40] chunks (shared across waves).
__global__ __launch_bounds__(512, 4) void attn_gemm2_fused(const bf16* q, const bf16* k,
      const bf16* Vtg, const bf16* u, const bf16* W2t, const float* bias,
      float* h, int mode, float* rms1, float* pooled_raw, float* outb, bf16* hb) {
  __shared__ char smem[77824];
  bf16* Ks = (bf16*)smem;            // [64][136]   (attn phase)
  bf16* Vt = (bf16*)(smem + 17408);  // [256][64] swizzled (attn phase)
  bf16* Ps = (bf16*)(smem + 50176);  // [128][72]   (attn phase)
  bf16* Os = (bf16*)smem;            // [128][264]  (gemm2 phase, overlays 0..67584)
  bf16* Wt = (bf16*)(smem + 67584);  // [128][40]   (gemm2 phase W2 chunk)

  int tid = threadIdx.x;
  int w = tid >> 6, l = tid & 63;
  int r = l & 15, g = l >> 4;
  int xcd = blockIdx.x & 7, j0 = blockIdx.x >> 3;
  int b  = xcd*16 + (j0 >> 2);
  int nt = j0 & 3;
  size_t rowbase = (size_t)b * T_;
  int n0 = nt * 128;

  bf16x8 qf[4];
  const bf16* qrow = q + (rowbase + n0 + 16*w + r) * S_ + g*8;
  #pragma unroll
  for (int kk=0; kk<4; kk++) qf[kk] = *(const bf16x8*)(qrow + kk*32);

  f32x4 oacc[16];
  #pragma unroll
  for (int i=0;i<16;i++) oacc[i] = (f32x4){0.f,0.f,0.f,0.f};

  for (int m0 = 0; m0 < T_; m0 += 64) {
    #pragma unroll
    for (int i=0;i<2;i++){
      int chunk = i*512 + tid;
      int row = chunk >> 4, c = chunk & 15;
      *(bf16x8*)(Ks + row*136 + c*8) =
        *(const bf16x8*)(k + (rowbase + m0 + row)*S_ + c*8);
    }
    #pragma unroll
    for (int i=0;i<4;i++){
      int chunk = i*512 + tid;
      int e = chunk >> 3, c = chunk & 7;
      *(bf16x8*)(Vt + e*64 + ((c ^ (e&7)) << 3)) =
        *(const bf16x8*)(Vtg + (size_t)b*131072 + (size_t)e*T_ + m0 + c*8);
    }
    __syncthreads();

    #pragma unroll
    for (int nf=0; nf<4; nf++){
      f32x4 sacc = (f32x4){0.f,0.f,0.f,0.f};
      #pragma unroll
      for (int kk=0; kk<4; kk++){
        bf16x8 kf = *(const bf16x8*)(Ks + (16*nf + r)*136 + kk*32 + g*8);
        sacc = __builtin_amdgcn_mfma_f32_16x16x32_bf16(qf[kk], kf, sacc, 0,0,0);
      }
      #pragma unroll
      for (int reg=0; reg<4; reg++){
        float t = fmaxf(sacc[reg] * (1.f/512.f), 0.f);
        Ps[(16*w + 4*g + reg)*72 + 16*nf + r] = f2b(t*t);
      }
    }
    #pragma unroll
    for (int ks=0; ks<2; ks++){
      bf16x8 pa = *(const bf16x8*)(Ps + (16*w + r)*72 + ks*32 + g*8);
      #pragma unroll
      for (int nf2=0; nf2<16; nf2++){
        int e = 16*nf2 + r;
        bf16x8 vb = *(const bf16x8*)(Vt + e*64 + (((4*ks + g) ^ (e&7)) << 3));
        oacc[nf2] = __builtin_amdgcn_mfma_f32_16x16x32_bf16(pa, vb, oacc[nf2], 0,0,0);
      }
    }
    __syncthreads();
  }

  // ---- Phase 2: Os = PV (scalar C-layout), coalesced u-multiply, then Os @ W2 ----
  size_t growbase = rowbase + n0;
  #pragma unroll
  for (int nf2=0; nf2<16; nf2++){
    #pragma unroll
    for (int reg=0; reg<4; reg++){
      Os[(16*w + 4*g + reg)*264 + 16*nf2 + r] = f2b(oacc[nf2][reg]);
    }
  }
  __syncthreads();
  #pragma unroll
  for (int i=0;i<8;i++){
    int chunk = i*512 + tid;
    int row = chunk >> 5, c = chunk & 31;
    bf16x8 uvv = *(const bf16x8*)(u + (growbase + row)*D_ + c*8);
    bf16x8 ov  = *(const bf16x8*)(Os + row*264 + c*8);
    bf16x8 res;
    #pragma unroll
    for (int e=0;e<8;e++)
      ((bf16*)&res)[e] = f2b(b2f(((bf16*)&ov)[e]) * b2f(((bf16*)&uvv)[e]));
    *(bf16x8*)(Os + row*264 + c*8) = res;
  }
  #pragma unroll
  for (int i=0;i<16;i++) oacc[i] = (f32x4){0.f,0.f,0.f,0.f};
  __syncthreads();

  for (int kc=0; kc<8; kc++){
    bf16x8 a0 = *(const bf16x8*)(Os + (16*w + r)*264 + kc*32 + g*8);
    #pragma unroll
    for (int nh=0; nh<2; nh++){
      __syncthreads();                       // prior chunk fully consumed
      {
        int rowW = tid>>2, ko = (tid&3)*8;
        *(bf16x8*)(Wt + rowW*40 + ko) =
          *(const bf16x8*)(W2t + (size_t)(128*nh + rowW)*256 + kc*32 + ko);
      }
      __syncthreads();
      #pragma unroll
      for (int nf2h=0; nf2h<8; nf2h++){
        bf16x8 bfr = *(const bf16x8*)(Wt + (16*nf2h + r)*40 + g*8);
        oacc[nh*8+nf2h] =
          __builtin_amdgcn_mfma_f32_16x16x32_bf16(a0, bfr, oacc[nh*8+nf2h], 0,0,0);
      }
    }
  }

  // ---- epilogue ----
  if (mode == 0) {
    #pragma unroll
    for (int reg=0; reg<4; reg++){
      size_t row = growbase + 16*w + 4*g + reg;
      float ssum = 0.f;
      #pragma unroll
      for (int nf2=0; nf2<16; nf2++){
        int col = 16*nf2 + r;
        float hv = h[row*D_ + col] + oacc[nf2][reg] + bias[col];
        h[row*D_ + col] = hv;
        hb[row*D_ + col] = f2b(hv);
        ssum += hv*hv;
      }
      ssum += __shfl_xor(ssum,1); ssum += __shfl_xor(ssum,2);
      ssum += __shfl_xor(ssum,4); ssum += __shfl_xor(ssum,8);
      if (r == 0) rms1[row] = ssum;   // full row in-wave: no atomic needed
    }
  } else {
    #pragma unroll
    for (int nf2=0; nf2<16; nf2++){
      int col = 16*nf2 + r;
      float bv = bias[col];
      float psum = 0.f;
      #pragma unroll
      for (int reg=0; reg<4; reg++){
        size_t row = growbase + 16*w + 4*g + reg;
        float hv = h[row*D_ + col] + oacc[nf2][reg] + bv;
        outb[row*D_ + col] = hv;
        float cv = fmaxf(hv, 1e-6f);
        psum += cv*cv*cv;
      }
      psum += __shfl_xor(psum,16); psum += __shfl_xor(psum,32);
      if (g == 0) atomicAdd(pooled_raw + b*D_ + col, psum);
    }
  }
}

// ---------------- emb: pooled=cbrt(raw/T); emb = norm(pooled@We+be) ----------------
__global__ __launch_bounds__(256) void emb_kernel(const float* pooled_raw, const float* We,
      const float* be, float* out) {
  __shared__ float pr[D_];
  __shared__ float red[256];
  int b = blockIdx.x, j = threadIdx.x;
  pr[j] = cbrtf(pooled_raw[b*D_+j] * (1.f/T_));
  __syncthreads();
  float acc = be[j];
  for (int kk=0;kk<D_;kk++) acc += pr[kk]*We[kk*D_+j];
  red[j] = acc*acc;
  __syncthreads();
  for (int off=128; off>0; off>>=1){
    if (j<off) red[j]+=red[j+off];
    __syncthreads();
  }
  out[b*D_+j] = acc * rsqrtf(red[0]);
}

extern "C" void kernel_launch(void* const* d_in, const int* in_sizes, int n_in,
                              void* d_out, int out_size, void* d_ws, size_t ws_size,
                              hipStream_t stream) {
  const float* x         = (const float*)d_in[0];
  const float* pe_scale  = (const float*)d_in[1];
  const float* W_in      = (const float*)d_in[2];
  const float* b_in      = (const float*)d_in[3];
  const float* norm_scale= (const float*)d_in[4];
  const float* W1        = (const float*)d_in[5];
  const float* b1        = (const float*)d_in[6];
  const float* gamma     = (const float*)d_in[7];
  const float* beta      = (const float*)d_in[8];
  const float* W2        = (const float*)d_in[9];
  const float* b2        = (const float*)d_in[10];
  const float* We        = (const float*)d_in[11];
  const float* be        = (const float*)d_in[12];

  char* ws = (char*)d_ws;
  float* h       = (float*)(ws);                      // 67,108,864 B
  bf16*  hb      = (bf16*)(ws + 67108864);            // 33,554,432 B
  bf16*  u       = (bf16*)(ws + 100663296);           // 33,554,432 B
  bf16*  Vtg     = (bf16*)(ws + 134217728);           // 33,554,432 B
  bf16*  q       = (bf16*)(ws + 184549376);           // 16,777,216 B
  bf16*  kbuf    = (bf16*)(ws + 201326592);           // 16,777,216 B
  float* pe_tab  = (float*)(ws + 218103808);          //     49,152 B
  float* rs_tab  = (float*)(ws + 218152960);          //    131,072 B
  float* rc_tab  = (float*)(ws + 218284032);          //    131,072 B
  float* pooled_raw = (float*)(ws + 218415104);       //    131,072 B
  float* rms0    = (float*)(ws + 218546176);          //    262,144 B
  float* rms1    = (float*)(ws + 218808320);          //    262,144 B
  bf16*  W1t     = (bf16*)(ws + 219070464);           //    655,360 B
  bf16*  W2t     = (bf16*)(ws + 219725824);           //    262,144 B

  tables_kernel<<<T_, 64, 0, stream>>>(pe_scale, pe_tab, rs_tab, rc_tab);
  prep_kernel<<<1280, 256, 0, stream>>>(W1, W2, W1t, W2t);
  init_kernel<<<BT_/256, 256, 0, stream>>>(rms1, pooled_raw);
  embed_kernel<<<BT_/8, 256, 0, stream>>>(x, pe_tab, W_in, b_in, h, rms0, hb);
  float* outb = (float*)d_out + B_*D_;
  for (int l=0; l<L_; l++) {
    gemm1_mfma<<<BT_/128*5, 256, 0, stream>>>(hb, W1t + (size_t)l*640*D_, b1 + l*640,
        l ? rms1 : rms0, norm_scale, l, gamma, beta, rs_tab, rc_tab, u, Vtg, q, kbuf);
    attn_gemm2_fused<<<B_*4, 512, 0, stream>>>(q, kbuf, Vtg, u,
        W2t + (size_t)l*D_*D_, b2 + l*D_, h, l, rms1, pooled_raw, outb, hb);
  }
  emb_kernel<<<B_, 256, 0, stream>>>(pooled_raw, We, be, (float*)d_out);
}

// Round 14
// 371.662 us; speedup vs baseline: 1.1167x; 1.1167x over previous
//
#include <hip/hip_runtime.h>
#include <hip/hip_bf16.h>

#define B_ 128
#define T_ 512
#define BIN_ 24
#define D_ 256
#define S_ 128
#define L_ 2
#define BT_ (B_*T_)

typedef __hip_bfloat16 bf16;
typedef __hip_bfloat162 bf162;
typedef __attribute__((ext_vector_type(8))) short bf16x8;
typedef __attribute__((ext_vector_type(4))) short s16x4;
typedef __attribute__((ext_vector_type(4))) float f32x4;

__device__ __forceinline__ float b2f(bf16 x){ return __bfloat162float(x); }
__device__ __forceinline__ bf16 f2b(float x){ return __float2bfloat16(x); }
__device__ __forceinline__ float swish(float v){
  float e = __builtin_amdgcn_exp2f(-1.442695040888963f * v);
  return v * __builtin_amdgcn_rcpf(1.f + e);
}
// async global->LDS, 16B per lane; lds dest is wave-uniform base (+lane*16 by HW)
__device__ __forceinline__ void gld16(const bf16* g, bf16* l){
  __builtin_amdgcn_global_load_lds(
      (const __attribute__((address_space(1))) void*)g,
      (__attribute__((address_space(3))) void*)l, 16, 0, 0);
}

// ---------------- tables: sinusoid PE (scaled) + rope sin/cos ----------------
__global__ void tables_kernel(const float* pe_scale_ptr, float* pe_tab, float* rs, float* rc) {
  int t = blockIdx.x;      // 0..511
  int j = threadIdx.x;     // 64 threads
  float ps = pe_scale_ptr[0];
  const float LOG1E4 = 9.210340371976184f;
  if (j < 64) {
    float inv = expf(-LOG1E4 * (float)j / 64.f);   // rope: 10000^(-2j/128)
    float ang = (float)t * inv;
    rs[t*64 + j] = sinf(ang);
    rc[t*64 + j] = cosf(ang);
  }
  if (j < BIN_) {
    int jj = (j < 12) ? j : (j - 12);
    float inv = expf(-LOG1E4 * (float)jj / 11.f);
    float ang = (float)t * inv;
    pe_tab[t*BIN_ + j] = ps * ((j < 12) ? sinf(ang) : cosf(ang));
  }
}

// ---------------- prep: W1 [2][256][640] -> W1t bf16 [2][640][256]; W2 likewise ----
__global__ __launch_bounds__(256) void prep_kernel(const float* W1, const float* W2,
                                                   bf16* W1t, bf16* W2t) {
  int idx = blockIdx.x*256 + threadIdx.x;
  if (idx < 2*256*640) {
    int l = idx / (256*640); int rem = idx % (256*640);
    int k = rem / 640; int n = rem % 640;
    W1t[(size_t)l*640*256 + n*256 + k] = f2b(W1[idx]);
  }
  if (idx < 2*256*256) {
    int l = idx >> 16; int rem = idx & 65535;
    int k = rem >> 8; int n = rem & 255;
    W2t[(size_t)l*65536 + n*256 + k] = f2b(W2[idx]);
  }
}

// ---------------- init: zero rms1 + pooled_raw ----------------
__global__ __launch_bounds__(256) void init_kernel(float* rms1, float* pooled_raw) {
  int i = blockIdx.x*256 + threadIdx.x;
  if (i < BT_) rms1[i] = 0.f;
  if (i < B_*D_) pooled_raw[i] = 0.f;
}

// ---------------- embed: h,hb = swish((x+pe)@W_in+b_in); rms0[row]=sum(h^2) --------
__global__ __launch_bounds__(256) void embed_kernel(const float* x, const float* pe_tab,
                const float* W_in, const float* b_in, float* h, float* rms0, bf16* hb) {
  __shared__ float xr[8][BIN_];
  __shared__ float wsum[4][8];
  int tid = threadIdx.x;
  int row0 = blockIdx.x * 8;
  if (tid < 8*BIN_) {
    int r = tid / BIN_, k = tid % BIN_;
    int row = row0 + r;
    int t = row & (T_-1);
    xr[r][k] = x[(size_t)row*BIN_ + k] + pe_tab[t*BIN_ + k];
  }
  __syncthreads();
  int d = tid;
  float bi = b_in[d];
  float acc[8];
  #pragma unroll
  for (int r=0;r<8;r++) acc[r]=bi;
  #pragma unroll
  for (int k=0;k<BIN_;k++){
    float w = W_in[k*D_ + d];
    #pragma unroll
    for (int r=0;r<8;r++) acc[r] += xr[r][k]*w;
  }
  float sq[8];
  #pragma unroll
  for (int r=0;r<8;r++){
    float v = swish(acc[r]);
    h[(size_t)(row0+r)*D_ + d] = v;
    hb[(size_t)(row0+r)*D_ + d] = f2b(v);
    sq[r] = v*v;
  }
  #pragma unroll
  for (int off=1; off<64; off<<=1)
    #pragma unroll
    for (int r=0;r<8;r++) sq[r] += __shfl_xor(sq[r], off);
  if ((tid&63)==0)
    #pragma unroll
    for (int r=0;r<8;r++) wsum[tid>>6][r] = sq[r];
  __syncthreads();
  if (tid < 8) rms0[row0+tid] = wsum[0][tid]+wsum[1][tid]+wsum[2][tid]+wsum[3][tid];
}

// ---------------- gemm1 (MFMA): [u|Vt_g|base] = swish(rms(h)@W1+b1)
// Staging via global_load_lds width=16 into LINEAR [128][64] LDS tiles with
// XOR-chunk swizzle (chunk ^= row&7): inverse-swizzled per-lane GLOBAL source,
// same XOR on fragment reads (rule: both-sides-or-neither).
__global__ __launch_bounds__(256) void gemm1_mfma(const bf16* A, const bf16* Bt,
      const float* bias, const float* rmsraw, const float* norm_scale, int l,
      bf16* u, bf16* Vtg, bf16* basebuf) {
  __shared__ char smem[34816];
  bf16* As  = (bf16*)smem;            // [128][64] linear (swizzled content)
  bf16* Bs  = (bf16*)(smem + 16384);  // [128][64]
  bf16* Ovl = (bf16*)smem;            // [128][136] epilogue overlay (34816 B)

  int tid = threadIdx.x;
  int w = tid>>6, lane = tid&63, r = lane&15, g = lane>>4;
  int wr = w>>1, wc = w&1;
  int dd = blockIdx.x; int xcd = dd&7, slot = dd>>3;
  int panel = xcd*64 + slot/5; int bx = slot%5;
  int row0 = panel*128, col0 = bx*128;

  // per-lane pre-swizzled source offsets (tr&7 == (lane>>3)&7 here)
  int trl = 8*w + (lane>>3);                    // + 32*i per step
  int tcg = ((lane&7) ^ ((lane>>3)&7)) * 8;     // swizzled column chunk (elements)

  f32x4 acc[4][4];
  #pragma unroll
  for (int i=0;i<4;i++)
    #pragma unroll
    for (int j=0;j<4;j++) acc[i][j] = (f32x4){0.f,0.f,0.f,0.f};

  for (int k0=0; k0<D_; k0+=64) {
    #pragma unroll
    for (int i=0;i<4;i++){
      int tr = 32*i + trl;
      gld16(A  + (size_t)(row0+tr)*D_ + k0 + tcg, As + (32*i + 8*w)*64);
      gld16(Bt + (size_t)(col0+tr)*D_ + k0 + tcg, Bs + (32*i + 8*w)*64);
    }
    __syncthreads();
    #pragma unroll
    for (int kk=0; kk<2; kk++){
      bf16x8 a[4], b[4];
      #pragma unroll
      for (int i=0;i<4;i++){
        int ch = ((kk*4 + g) ^ (r&7)) * 8;
        a[i] = *(const bf16x8*)(As + (64*wr+16*i+r)*64 + ch);
        b[i] = *(const bf16x8*)(Bs + (64*wc+16*i+r)*64 + ch);
      }
      #pragma unroll
      for (int i=0;i<4;i++)
        #pragma unroll
        for (int j=0;j<4;j++)
          acc[i][j] = __builtin_amdgcn_mfma_f32_16x16x32_bf16(a[i], b[j], acc[i][j], 0,0,0);
    }
    __syncthreads();
  }

  float ns = norm_scale[l];
  #pragma unroll
  for (int i=0;i<4;i++){
    size_t grow0 = row0 + 64*wr + 16*i + 4*g;
    float4 rv = *(const float4*)(rmsraw + grow0);
    float sc[4];
    sc[0] = rsqrtf(rv.x*(1.f/D_) + 1e-6f) * ns;
    sc[1] = rsqrtf(rv.y*(1.f/D_) + 1e-6f) * ns;
    sc[2] = rsqrtf(rv.z*(1.f/D_) + 1e-6f) * ns;
    sc[3] = rsqrtf(rv.w*(1.f/D_) + 1e-6f) * ns;
    #pragma unroll
    for (int j=0;j<4;j++){
      int gcol = col0 + 64*wc + 16*j + r;
      float bv = bias[gcol];
      if (bx < 2) {
        #pragma unroll
        for (int reg=0; reg<4; reg++){
          float v = swish(acc[i][j][reg]*sc[reg] + bv);
          u[(grow0+reg)*D_ + gcol] = f2b(v);
        }
      } else if (bx < 4) {
        #pragma unroll
        for (int reg=0; reg<4; reg++){
          float v = swish(acc[i][j][reg]*sc[reg] + bv);
          Ovl[(64*wc+16*j+r)*136 + (64*wr+16*i+4*g+reg)] = f2b(v);
        }
      } else {
        #pragma unroll
        for (int reg=0; reg<4; reg++){
          float v = swish(acc[i][j][reg]*sc[reg] + bv);
          basebuf[(grow0+reg)*S_ + (gcol-512)] = f2b(v);
        }
      }
    }
  }

  if (bx == 2 || bx == 3) {
    __syncthreads();
    size_t bb = row0 >> 9;
    int mg = row0 & 511;
    #pragma unroll
    for (int c=0;c<8;c++){
      int chunk = c*256 + tid;
      int e = chunk >> 4, mloc = (chunk & 15)*8;
      *(bf16x8*)(Vtg + bb*131072 + (size_t)(col0-256+e)*T_ + mg + mloc) =
        *(const bf16x8*)(Ovl + e*136 + mloc);
    }
  }
}

// ---------------- qk: rope(base*gamma+beta) for q and k ----------------
__global__ __launch_bounds__(256) void qk_kernel(const bf16* basebuf, const float* gamma, const float* beta,
      int l, const float* rs, const float* rc, bf16* q, bf16* k) {
  int tid = threadIdx.x;
  int j = tid & 127;
  size_t row = (size_t)blockIdx.x*2 + (tid>>7);
  int t = (int)(row & (T_-1));
  int j2 = j ^ 64;
  float v0 = b2f(basebuf[row*S_ + j]);
  float v1 = b2f(basebuf[row*S_ + j2]);
  int jm = j & 63;
  float sn = rs[t*64 + jm], cs = rc[t*64 + jm];
  float sgn = (j < 64) ? -1.f : 1.f;
  const float* g  = gamma + l*2*S_;
  const float* bt = beta  + l*2*S_;
  float xq = v0*g[j]      + bt[j];
  float pq = v1*g[j2]     + bt[j2];
  q[row*S_ + j] = f2b(xq*cs + sgn*pq*sn);
  float xk = v0*g[S_+j]   + bt[S_+j];
  float pk = v1*g[S_+j2]  + bt[S_+j2];
  k[row*S_ + j] = f2b(xk*cs + sgn*pk*sn);
}

// ---------------- attn+gemm2 fused: h += (u ⊙ (relu(qk^T/512)^2 @ v)) @ W2 + b2
// LDS 77824 -> 2 blocks/CU. Phase 2: Os=PV via LDS, coalesced u-multiply pass,
// then Os @ W2 with Wt[128][40] chunks (shared across waves).
__global__ __launch_bounds__(512, 4) void attn_gemm2_fused(const bf16* q, const bf16* k,
      const bf16* Vtg, const bf16* u, const bf16* W2t, const float* bias,
      float* h, int mode, float* rms1, float* pooled_raw, float* outb, bf16* hb) {
  __shared__ char smem[77824];
  bf16* Ks = (bf16*)smem;            // [64][136]   (attn phase)
  bf16* Vt = (bf16*)(smem + 17408);  // [256][64] swizzled (attn phase)
  bf16* Ps = (bf16*)(smem + 50176);  // [128][72]   (attn phase)
  bf16* Os = (bf16*)smem;            // [128][264]  (gemm2 phase, overlays 0..67584)
  bf16* Wt = (bf16*)(smem + 67584);  // [128][40]   (gemm2 phase W2 chunk)

  int tid = threadIdx.x;
  int w = tid >> 6, l = tid & 63;
  int r = l & 15, g = l >> 4;
  int xcd = blockIdx.x & 7, j0 = blockIdx.x >> 3;
  int b  = xcd*16 + (j0 >> 2);
  int nt = j0 & 3;
  size_t rowbase = (size_t)b * T_;
  int n0 = nt * 128;

  bf16x8 qf[4];
  const bf16* qrow = q + (rowbase + n0 + 16*w + r) * S_ + g*8;
  #pragma unroll
  for (int kk=0; kk<4; kk++) qf[kk] = *(const bf16x8*)(qrow + kk*32);

  f32x4 oacc[16];
  #pragma unroll
  for (int i=0;i<16;i++) oacc[i] = (f32x4){0.f,0.f,0.f,0.f};

  for (int m0 = 0; m0 < T_; m0 += 64) {
    #pragma unroll
    for (int i=0;i<2;i++){
      int chunk = i*512 + tid;
      int row = chunk >> 4, c = chunk & 15;
      *(bf16x8*)(Ks + row*136 + c*8) =
        *(const bf16x8*)(k + (rowbase + m0 + row)*S_ + c*8);
    }
    #pragma unroll
    for (int i=0;i<4;i++){
      int chunk = i*512 + tid;
      int e = chunk >> 3, c = chunk & 7;
      *(bf16x8*)(Vt + e*64 + ((c ^ (e&7)) << 3)) =
        *(const bf16x8*)(Vtg + (size_t)b*131072 + (size_t)e*T_ + m0 + c*8);
    }
    __syncthreads();

    #pragma unroll
    for (int nf=0; nf<4; nf++){
      f32x4 sacc = (f32x4){0.f,0.f,0.f,0.f};
      #pragma unroll
      for (int kk=0; kk<4; kk++){
        bf16x8 kf = *(const bf16x8*)(Ks + (16*nf + r)*136 + kk*32 + g*8);
        sacc = __builtin_amdgcn_mfma_f32_16x16x32_bf16(qf[kk], kf, sacc, 0,0,0);
      }
      #pragma unroll
      for (int reg=0; reg<4; reg++){
        float t = fmaxf(sacc[reg] * (1.f/512.f), 0.f);
        Ps[(16*w + 4*g + reg)*72 + 16*nf + r] = f2b(t*t);
      }
    }
    #pragma unroll
    for (int ks=0; ks<2; ks++){
      bf16x8 pa = *(const bf16x8*)(Ps + (16*w + r)*72 + ks*32 + g*8);
      #pragma unroll
      for (int nf2=0; nf2<16; nf2++){
        int e = 16*nf2 + r;
        bf16x8 vb = *(const bf16x8*)(Vt + e*64 + (((4*ks + g) ^ (e&7)) << 3));
        oacc[nf2] = __builtin_amdgcn_mfma_f32_16x16x32_bf16(pa, vb, oacc[nf2], 0,0,0);
      }
    }
    __syncthreads();
  }

  // ---- Phase 2: Os = PV (scalar C-layout), coalesced u-multiply, then Os @ W2 ----
  size_t growbase = rowbase + n0;
  #pragma unroll
  for (int nf2=0; nf2<16; nf2++){
    #pragma unroll
    for (int reg=0; reg<4; reg++){
      Os[(16*w + 4*g + reg)*264 + 16*nf2 + r] = f2b(oacc[nf2][reg]);
    }
  }
  __syncthreads();
  #pragma unroll
  for (int i=0;i<8;i++){
    int chunk = i*512 + tid;
    int row = chunk >> 5, c = chunk & 31;
    bf16x8 uvv = *(const bf16x8*)(u + (growbase + row)*D_ + c*8);
    bf16x8 ov  = *(const bf16x8*)(Os + row*264 + c*8);
    bf16x8 res;
    #pragma unroll
    for (int e=0;e<8;e++)
      ((bf16*)&res)[e] = f2b(b2f(((bf16*)&ov)[e]) * b2f(((bf16*)&uvv)[e]));
    *(bf16x8*)(Os + row*264 + c*8) = res;
  }
  #pragma unroll
  for (int i=0;i<16;i++) oacc[i] = (f32x4){0.f,0.f,0.f,0.f};
  __syncthreads();

  for (int kc=0; kc<8; kc++){
    bf16x8 a0 = *(const bf16x8*)(Os + (16*w + r)*264 + kc*32 + g*8);
    #pragma unroll
    for (int nh=0; nh<2; nh++){
      __syncthreads();                       // prior chunk fully consumed
      {
        int rowW = tid>>2, ko = (tid&3)*8;
        *(bf16x8*)(Wt + rowW*40 + ko) =
          *(const bf16x8*)(W2t + (size_t)(128*nh + rowW)*256 + kc*32 + ko);
      }
      __syncthreads();
      #pragma unroll
      for (int nf2h=0; nf2h<8; nf2h++){
        bf16x8 bfr = *(const bf16x8*)(Wt + (16*nf2h + r)*40 + g*8);
        oacc[nh*8+nf2h] =
          __builtin_amdgcn_mfma_f32_16x16x32_bf16(a0, bfr, oacc[nh*8+nf2h], 0,0,0);
      }
    }
  }

  // ---- epilogue ----
  if (mode == 0) {
    #pragma unroll
    for (int reg=0; reg<4; reg++){
      size_t row = growbase + 16*w + 4*g + reg;
      float ssum = 0.f;
      #pragma unroll
      for (int nf2=0; nf2<16; nf2++){
        int col = 16*nf2 + r;
        float hv = h[row*D_ + col] + oacc[nf2][reg] + bias[col];
        h[row*D_ + col] = hv;
        hb[row*D_ + col] = f2b(hv);
        ssum += hv*hv;
      }
      ssum += __shfl_xor(ssum,1); ssum += __shfl_xor(ssum,2);
      ssum += __shfl_xor(ssum,4); ssum += __shfl_xor(ssum,8);
      if (r == 0) rms1[row] = ssum;   // full row in-wave: no atomic needed
    }
  } else {
    #pragma unroll
    for (int nf2=0; nf2<16; nf2++){
      int col = 16*nf2 + r;
      float bv = bias[col];
      float psum = 0.f;
      #pragma unroll
      for (int reg=0; reg<4; reg++){
        size_t row = growbase + 16*w + 4*g + reg;
        float hv = h[row*D_ + col] + oacc[nf2][reg] + bv;
        outb[row*D_ + col] = hv;
        float cv = fmaxf(hv, 1e-6f);
        psum += cv*cv*cv;
      }
      psum += __shfl_xor(psum,16); psum += __shfl_xor(psum,32);
      if (g == 0) atomicAdd(pooled_raw + b*D_ + col, psum);
    }
  }
}

// ---------------- emb: pooled=cbrt(raw/T); emb = norm(pooled@We+be) ----------------
__global__ __launch_bounds__(256) void emb_kernel(const float* pooled_raw, const float* We,
      const float* be, float* out) {
  __shared__ float pr[D_];
  __shared__ float red[256];
  int b = blockIdx.x, j = threadIdx.x;
  pr[j] = cbrtf(pooled_raw[b*D_+j] * (1.f/T_));
  __syncthreads();
  float acc = be[j];
  for (int kk=0;kk<D_;kk++) acc += pr[kk]*We[kk*D_+j];
  red[j] = acc*acc;
  __syncthreads();
  for (int off=128; off>0; off>>=1){
    if (j<off) red[j]+=red[j+off];
    __syncthreads();
  }
  out[b*D_+j] = acc * rsqrtf(red[0]);
}

extern "C" void kernel_launch(void* const* d_in, const int* in_sizes, int n_in,
                              void* d_out, int out_size, void* d_ws, size_t ws_size,
                              hipStream_t stream) {
  const float* x         = (const float*)d_in[0];
  const float* pe_scale  = (const float*)d_in[1];
  const float* W_in      = (const float*)d_in[2];
  const float* b_in      = (const float*)d_in[3];
  const float* norm_scale= (const float*)d_in[4];
  const float* W1        = (const float*)d_in[5];
  const float* b1        = (const float*)d_in[6];
  const float* gamma     = (const float*)d_in[7];
  const float* beta      = (const float*)d_in[8];
  const float* W2        = (const float*)d_in[9];
  const float* b2        = (const float*)d_in[10];
  const float* We        = (const float*)d_in[11];
  const float* be        = (const float*)d_in[12];

  char* ws = (char*)d_ws;
  float* h       = (float*)(ws);                      // 67,108,864 B
  bf16*  hb      = (bf16*)(ws + 67108864);            // 33,554,432 B
  bf16*  u       = (bf16*)(ws + 100663296);           // 33,554,432 B
  bf16*  Vtg     = (bf16*)(ws + 134217728);           // 33,554,432 B
  bf16*  basebuf = (bf16*)(ws + 167772160);           // 16,777,216 B
  bf16*  q       = (bf16*)(ws + 184549376);           // 16,777,216 B
  bf16*  kbuf    = (bf16*)(ws + 201326592);           // 16,777,216 B
  float* pe_tab  = (float*)(ws + 218103808);          //     49,152 B
  float* rs_tab  = (float*)(ws + 218152960);          //    131,072 B
  float* rc_tab  = (float*)(ws + 218284032);          //    131,072 B
  float* pooled_raw = (float*)(ws + 218415104);       //    131,072 B
  float* rms0    = (float*)(ws + 218546176);          //    262,144 B
  float* rms1    = (float*)(ws + 218808320);          //    262,144 B
  bf16*  W1t     = (bf16*)(ws + 219070464);           //    655,360 B
  bf16*  W2t     = (bf16*)(ws + 219725824);           //    262,144 B

  tables_kernel<<<T_, 64, 0, stream>>>(pe_scale, pe_tab, rs_tab, rc_tab);
  prep_kernel<<<1280, 256, 0, stream>>>(W1, W2, W1t, W2t);
  init_kernel<<<BT_/256, 256, 0, stream>>>(rms1, pooled_raw);
  embed_kernel<<<BT_/8, 256, 0, stream>>>(x, pe_tab, W_in, b_in, h, rms0, hb);
  float* outb = (float*)d_out + B_*D_;
  for (int l=0; l<L_; l++) {
    gemm1_mfma<<<BT_/128*5, 256, 0, stream>>>(hb, W1t + (size_t)l*640*D_, b1 + l*640,
        l ? rms1 : rms0, norm_scale, l, u, Vtg, basebuf);
    qk_kernel<<<BT_/2, 256, 0, stream>>>(basebuf, gamma, beta, l, rs_tab, rc_tab, q, kbuf);
    attn_gemm2_fused<<<B_*4, 512, 0, stream>>>(q, kbuf, Vtg, u,
        W2t + (size_t)l*D_*D_, b2 + l*D_, h, l, rms1, pooled_raw, outb, hb);
  }
  emb_kernel<<<B_, 256, 0, stream>>>(pooled_raw, We, be, (float*)d_out);
}